// Round 17
// baseline (644.959 us; speedup 1.0000x reference)
//
#include <hip/hip_runtime.h>
#include <cstdint>
#include <cstddef>

#define NNODES 50000
#define NPAD   50048        // 391*128, padded M for P/Q GEMM
#define NRELS  256
#define DIM    256
#define TT     24
#define EE     20000
#define BATCH  16
#define SEQQ   7

typedef __bf16 bf16;
typedef __bf16 bf16x4 __attribute__((ext_vector_type(4)));
typedef __bf16 bf16x8 __attribute__((ext_vector_type(8)));
typedef float  f32x4  __attribute__((ext_vector_type(4)));

// async global->LDS, 16B per lane; LDS dest is wave-uniform base (+lane*16 by HW);
// the GLOBAL source address is per-lane (m173).
__device__ __forceinline__ void gload16(const void* g, void* l){
  __builtin_amdgcn_global_load_lds((const __attribute__((address_space(1))) void*)g,
                                   (__attribute__((address_space(3))) void*)l, 16, 0, 0);
}

// ---------------- prep kernels ----------------

__global__ void k_cvt8(const float* __restrict__ in, bf16* __restrict__ out, int n8){
  int i = blockIdx.x*256 + threadIdx.x;
  if (i >= n8) return;
  const float4* p = (const float4*)in + (size_t)i*2;
  float4 a = p[0], b = p[1];
  bf16x8 o;
  o[0]=(bf16)a.x; o[1]=(bf16)a.y; o[2]=(bf16)a.z; o[3]=(bf16)a.w;
  o[4]=(bf16)b.x; o[5]=(bf16)b.y; o[6]=(bf16)b.z; o[7]=(bf16)b.w;
  ((bf16x8*)out)[i] = o;
}

// Fused edge weight, transposed: WbT[n][k], k in [0,768) = [W1 | W2fold | W3].
__global__ void k_build_wbt(const float* __restrict__ tW, const float* __restrict__ eW,
                            bf16* __restrict__ WbT){
  int n = blockIdx.x, j = threadIdx.x;
  WbT[(size_t)n*768 + j]       = (bf16)eW[(size_t)j*256 + n];
  WbT[(size_t)n*768 + 512 + j] = (bf16)eW[(size_t)(512+j)*256 + n];
  float acc = 0.f;
  for (int m=0; m<256; ++m) acc += tW[(size_t)j*256 + m] * eW[(size_t)(256+m)*256 + n];
  WbT[(size_t)n*768 + 256 + j] = (bf16)acc;
}

// fused bias: bfused[n] = edge_w_b[n] + sum_m text_w_b[m]*W2[m][n]
__global__ void k_bias(const float* __restrict__ tb, const float* __restrict__ eW,
                       const float* __restrict__ eb, float* __restrict__ bf){
  int n = threadIdx.x;
  float acc = eb[n];
  for (int m=0; m<256; ++m) acc += tb[m] * eW[(size_t)(256+m)*256 + n];
  bf[n] = acc;
}

// gru weight [256][768] -> transposed bf16 [768][256]
__global__ void k_gruWT(const float* __restrict__ W, bf16* __restrict__ WT){
  int n = blockIdx.x, k = threadIdx.x;
  WT[(size_t)n*256 + k] = (bf16)W[(size_t)k*768 + n];
}

// per-t histogram of rels + exclusive scan
__global__ void k_hist(const int* __restrict__ rel, int* __restrict__ counts,
                       int* __restrict__ offs, int* __restrict__ cursor){
  __shared__ int hist[256];
  __shared__ int scan[256];
  int t = blockIdx.x, tid = threadIdx.x;
  hist[tid] = 0;
  __syncthreads();
  for (int e = tid; e < EE; e += 256) atomicAdd(&hist[rel[(size_t)t*EE + e]], 1);
  __syncthreads();
  int v = hist[tid];
  scan[tid] = v;
  __syncthreads();
  for (int d=1; d<256; d<<=1){
    int add = (tid >= d) ? scan[tid-d] : 0;
    __syncthreads();
    scan[tid] += add;
    __syncthreads();
  }
  int ex = scan[tid] - v;
  counts[t*256+tid] = v;
  offs[t*256+tid]   = ex;
  cursor[t*256+tid] = ex;
}

// bucket edges by (t,rel): emit global text row index, src/dst ids, and tr id
__global__ void k_perm(const int* __restrict__ rel, const int* __restrict__ esrc,
                       const int* __restrict__ edst, int* __restrict__ cursor,
                       int* __restrict__ gperm, int* __restrict__ src_p,
                       int* __restrict__ dst_p, int* __restrict__ tr_p){
  int t = blockIdx.y;
  int e = blockIdx.x*256 + threadIdx.x;
  if (e < EE){
    int r = rel[(size_t)t*EE + e];
    int p = atomicAdd(&cursor[t*256 + r], 1);
    size_t g = (size_t)t*EE + p;
    gperm[g] = t*EE + e;
    src_p[g] = esrc[(size_t)t*EE + e];
    dst_p[g] = edst[(size_t)t*EE + e];
    tr_p[g]  = t*256 + r;
  }
}

// gather-permute-convert text rows into SORTED, PRE-SWIZZLED bf16 layout.
// One 64-lane wave per sorted row g (full 1KB row read: lane l = float4 at 4l).
// Dest swizzle (within-512B): src 16B-part p = l>>1 -> stored part
// pd = (p&24) | ((p^g)&7); 8B half selected by l&1. Write stays one 512B
// transaction per wave. Pure-gather kernel: huge TLP, no compute phase ->
// random-row reads run at full achievable BW (r3-proven shape).
__global__ void k_textp(const float* __restrict__ text, const int* __restrict__ gperm,
                        bf16* __restrict__ tp){
  int g = blockIdx.x*4 + (threadIdx.x >> 6);   // sorted row index
  int l = threadIdx.x & 63;
  int e = gperm[g];                             // global text row (t*EE+e)
  float4 v = ((const float4*)(text + (size_t)e*256))[l];
  bf16x4 o;
  o[0]=(bf16)v.x; o[1]=(bf16)v.y; o[2]=(bf16)v.z; o[3]=(bf16)v.w;
  int p  = l >> 1;
  int pd = (p & 24) | ((p ^ g) & 7);
  *(bf16x4*)((char*)tp + (size_t)g*512 + (size_t)pd*16 + (size_t)(l&1)*8) = o;
}

// ---------------- node projection GEMM (swapped operands, coalesced stores) ----
__global__ __launch_bounds__(256) void k_projn(
    const bf16* __restrict__ Abf, const bf16* __restrict__ WbT, int koff,
    bf16* __restrict__ out)
{
  int m0 = blockIdx.x*128;
  int tid = threadIdx.x, lane = tid&63, w = tid>>6;
  int l15 = lane&15, lq = lane>>4;
  int c0 = w*64;
  __shared__ __align__(16) bf16 Al[128*32];   // 8KB
  __shared__ __align__(16) bf16 Bl[256*32];   // 16KB

  f32x4 acc[8][4];
  f32x4 z4 = {0.f,0.f,0.f,0.f};
  #pragma unroll
  for (int mi=0;mi<8;++mi)
    #pragma unroll
    for (int ni=0;ni<4;++ni) acc[mi][ni]=z4;

  for (int ks=0; ks<8; ++ks){
    int k0 = ks*32;
    #pragma unroll
    for (int p=0;p<2;++p){
      int c = p*256 + tid;
      int rw = c>>2, prt = c&3;
      int pp = prt ^ ((rw>>1)&3);
      const char* src = (const char*)(Abf + (size_t)(m0+rw)*256 + k0) + pp*16;
      gload16(src, (char*)Al + (size_t)(p*256 + w*64)*16);
    }
    #pragma unroll
    for (int p=0;p<4;++p){
      int c = p*256 + tid;
      int nn = c>>2, prt = c&3;
      int pp = prt ^ ((nn>>1)&3);
      const char* src = (const char*)(WbT + (size_t)nn*768 + koff + k0) + pp*16;
      gload16(src, (char*)Bl + (size_t)(p*256 + w*64)*16);
    }
    __syncthreads();
    bf16x8 b[4];
    #pragma unroll
    for (int ni=0;ni<4;++ni){
      int nn = c0 + ni*16 + l15;
      b[ni] = *(const bf16x8*)((const char*)Bl + (size_t)nn*64 + (size_t)((lq ^ ((nn>>1)&3))*16));
    }
    #pragma unroll
    for (int mi=0;mi<8;++mi){
      int rw = mi*16 + l15;
      bf16x8 a = *(const bf16x8*)((const char*)Al + (size_t)rw*64 + (size_t)((lq ^ ((rw>>1)&3))*16));
      #pragma unroll
      for (int ni=0;ni<4;++ni)
        acc[mi][ni] = __builtin_amdgcn_mfma_f32_16x16x32_bf16(b[ni], a, acc[mi][ni], 0,0,0);
    }
    __syncthreads();
  }
  #pragma unroll
  for (int mi=0;mi<8;++mi){
    int row = m0 + mi*16 + l15;
    #pragma unroll
    for (int ni=0;ni<4;++ni){
      bf16x4 o;
      #pragma unroll
      for (int q=0;q<4;++q) o[q] = (bf16)acc[mi][ni][q];
      *(bf16x4*)(out + (size_t)row*256 + c0 + ni*16 + lq*4) = o;
    }
  }
}

// ---- fused text projection + gather-add-relu + segment-sum ----
// A operand is now a SEQUENTIAL bf16 stream (text_bp, sorted + pre-swizzled):
// stage the full 64-row x 512B tile linearly (8 gload16/thread), one barrier,
// then ALL 8 MFMA k-steps barrier-free (no cvt). B = per-lane register loads
// from L2. Read-side swizzle matches k_textp's write: part p = ks*4+lq of
// row rw lives at slot (p&24)|((p^rw)&7)  (m0 % 64 == 0 keeps g<->rw phase).
__global__ __launch_bounds__(256,3) void k_projtc(
    const bf16* __restrict__ tp, const bf16* __restrict__ WbT,
    const float* __restrict__ bfused,
    const bf16* __restrict__ P, const bf16* __restrict__ Q,
    const int* __restrict__ src_p, const int* __restrict__ dst_p,
    const int* __restrict__ tr_p, float* __restrict__ rel_sum)
{
  int m0 = blockIdx.x*64;
  int tid = threadIdx.x, lane = tid&63, w = tid>>6;
  int l15 = lane&15, lq = lane>>4;
  int c0 = w*64;
  __shared__ __align__(16) bf16 Atl[64*256];   // 32KB: full bf16 A tile (swizzled)
  __shared__ int trA[64], sIl[64], dIl[64];
  __shared__ int runS[65], runT[64];
  __shared__ int nRunS;

  if (tid < 64){
    int g = m0 + tid;
    trA[tid] = tr_p[g];
    sIl[tid] = src_p[g];
    dIl[tid] = dst_p[g];
  }
  __syncthreads();
  // stage the whole tile linearly while tid0 scans runs
  {
    const char* srcT = (const char*)tp + (size_t)m0*512;
    #pragma unroll
    for (int j=0;j<8;++j){
      gload16(srcT + (size_t)(j*256 + tid)*16,
              (char*)Atl + (size_t)(j*256 + w*64)*16);
    }
  }
  if (tid == 0){
    int nR = 0;
    for (int i=0;i<64;++i){
      if (i==0 || trA[i]!=trA[i-1]){ runS[nR]=i; runT[nR]=trA[i]; ++nR; }
    }
    runS[nR] = 64;
    nRunS = nR;
  }
  __syncthreads();   // drains staging vmcnt + tid0's LDS writes

  // B direct-load base: lane's rows are c0+ni*16+l15, chunk at ks*32+lq*8
  const bf16* bBase = WbT + (size_t)(c0 + l15)*768 + 256 + lq*8;

  f32x4 acc[4][4];
  f32x4 z4 = {0.f,0.f,0.f,0.f};
  #pragma unroll
  for (int mi=0;mi<4;++mi)
    #pragma unroll
    for (int ni=0;ni<4;++ni) acc[mi][ni]=z4;

  #pragma unroll
  for (int ks=0; ks<8; ++ks){
    bf16x8 b[4];
    #pragma unroll
    for (int ni=0;ni<4;++ni)
      b[ni] = *(const bf16x8*)(bBase + (size_t)ni*16*768 + ks*32);
    bf16x8 a[4];
    int p = ks*4 + lq;
    #pragma unroll
    for (int mi=0;mi<4;++mi){
      int rw = mi*16 + l15;
      int sp = (p & 24) | ((p ^ rw) & 7);
      a[mi] = *(const bf16x8*)((const char*)Atl + (size_t)rw*512 + (size_t)sp*16);
    }
    #pragma unroll
    for (int mi=0;mi<4;++mi)
      #pragma unroll
      for (int ni=0;ni<4;++ni)
        acc[mi][ni] = __builtin_amdgcn_mfma_f32_16x16x32_bf16(b[ni], a[mi], acc[mi][ni], 0,0,0);
  }

  // ---- epilogue: add P[src]+Q[dst]+bias, relu in place ----
  float4 bias4[4];
  #pragma unroll
  for (int ni=0;ni<4;++ni)
    bias4[ni] = *(const float4*)(bfused + c0 + ni*16 + lq*4);

  #pragma unroll
  for (int mi=0;mi<4;++mi){
    int row = mi*16 + l15;
    int srow = sIl[row], drow = dIl[row];
    #pragma unroll
    for (int ni=0;ni<4;++ni){
      bf16x4 pv = *(const bf16x4*)(P + (size_t)srow*256 + c0 + ni*16 + lq*4);
      bf16x4 qv = *(const bf16x4*)(Q + (size_t)drow*256 + c0 + ni*16 + lq*4);
      f32x4 t4 = acc[mi][ni];
      t4[0] = fmaxf(t4[0] + (float)pv[0] + (float)qv[0] + bias4[ni].x, 0.f);
      t4[1] = fmaxf(t4[1] + (float)pv[1] + (float)qv[1] + bias4[ni].y, 0.f);
      t4[2] = fmaxf(t4[2] + (float)pv[2] + (float)qv[2] + bias4[ni].z, 0.f);
      t4[3] = fmaxf(t4[3] + (float)pv[3] + (float)qv[3] + bias4[ni].w, 0.f);
      acc[mi][ni] = t4;
    }
  }

  // ---- segment reduce per run (r6-verified mapping) ----
  int nR = nRunS;
  for (int k=0; k<nR; ++k){
    int rs = runS[k], re = runS[k+1], tr = runT[k];
    float part16[16];
    #pragma unroll
    for (int ni=0;ni<4;++ni){
      #pragma unroll
      for (int q=0;q<4;++q){
        float s = 0.f;
        #pragma unroll
        for (int mi=0;mi<4;++mi){
          int row = mi*16 + l15;
          s += (row >= rs && row < re) ? acc[mi][ni][q] : 0.f;
        }
        part16[ni*4+q] = s;
      }
    }
    #pragma unroll
    for (int m=1; m<16; m<<=1){
      #pragma unroll
      for (int s=0;s<16;++s) part16[s] += __shfl_xor(part16[s], m);
    }
    float v = part16[0];
    #pragma unroll
    for (int s=1;s<16;++s) v = (l15==s) ? part16[s] : v;
    atomicAdd(&rel_sum[(size_t)tr*256 + c0 + ((l15>>2)<<4) + (lq<<2) + (l15&3)], v);
  }
}

// rel_bf[tr][c] = bf16(rel_sum/count) or 0
__global__ void k_mean(const float* __restrict__ rel_sum, const int* __restrict__ counts,
                       bf16* __restrict__ rel_bf){
  int tr = blockIdx.x, c = threadIdx.x;
  int cnt = counts[tr];
  float v = (cnt > 0) ? rel_sum[(size_t)tr*256 + c] / (float)cnt : 0.f;
  rel_bf[(size_t)tr*256 + c] = (bf16)v;
}

// ---------------- plain bf16 GEMM (GI), K=256, out f32 stride 768 ----------------
__global__ __launch_bounds__(256) void k_gemm(
    const bf16* __restrict__ A, const bf16* __restrict__ BT,
    const float* __restrict__ bias, float* __restrict__ Out)
{
  int m0 = blockIdx.x*128, n0 = blockIdx.y*128;
  int tid = threadIdx.x, lane = tid&63, w = tid>>6;
  int l15 = lane&15, lq = lane>>4;
  __shared__ __align__(16) bf16 Al[128*32];
  __shared__ __align__(16) bf16 Bl[128*32];
  int wr = (w&1)*64, wc = (w>>1)*64;
  f32x4 acc[4][4];
  f32x4 z4 = {0.f,0.f,0.f,0.f};
  #pragma unroll
  for (int mi=0;mi<4;++mi)
    #pragma unroll
    for (int ni=0;ni<4;++ni) acc[mi][ni]=z4;
  for (int ks=0; ks<8; ++ks){
    int k0 = ks*32;
    #pragma unroll
    for (int p=0;p<2;++p){
      int c = p*256 + tid;
      int rw = c>>2, part = c&3;
      int pp = part ^ ((rw>>1)&3);
      const char* src = (const char*)(A + (size_t)(m0+rw)*256 + k0) + pp*16;
      gload16(src, (char*)Al + (size_t)(p*256 + w*64)*16);
    }
    #pragma unroll
    for (int p=0;p<2;++p){
      int c = p*256 + tid;
      int nn = c>>2, part = c&3;
      int pp = part ^ ((nn>>1)&3);
      const char* src = (const char*)(BT + (size_t)(n0+nn)*256 + k0) + pp*16;
      gload16(src, (char*)Bl + (size_t)(p*256 + w*64)*16);
    }
    __syncthreads();
    bf16x8 a[4], b[4];
    #pragma unroll
    for (int mi=0;mi<4;++mi){
      int rw = wr + mi*16 + l15;
      a[mi] = *(const bf16x8*)((const char*)Al + (size_t)rw*64 + (size_t)((lq ^ ((rw>>1)&3))*16));
    }
    #pragma unroll
    for (int ni=0;ni<4;++ni){
      int nn = wc + ni*16 + l15;
      b[ni] = *(const bf16x8*)((const char*)Bl + (size_t)nn*64 + (size_t)((lq ^ ((nn>>1)&3))*16));
    }
    #pragma unroll
    for (int mi=0;mi<4;++mi)
      #pragma unroll
      for (int ni=0;ni<4;++ni)
        acc[mi][ni] = __builtin_amdgcn_mfma_f32_16x16x32_bf16(a[mi], b[ni], acc[mi][ni], 0,0,0);
    __syncthreads();
  }
  #pragma unroll
  for (int ni=0;ni<4;++ni){
    int col = n0 + wc + ni*16 + l15;
    float bv = bias[col];
    #pragma unroll
    for (int mi=0;mi<4;++mi){
      #pragma unroll
      for (int q=0;q<4;++q){
        int row = m0 + wr + mi*16 + lq*4 + q;
        Out[(size_t)row*768 + col] = acc[mi][ni][q] + bv;
      }
    }
  }
}

// ---------------- fused whole-sequence GRU ----------------
__global__ __launch_bounds__(256) void k_gru(
    const float* __restrict__ GI, const bf16* __restrict__ WhhT,
    const float* __restrict__ bhh, const int* __restrict__ time_idx,
    float* __restrict__ out)
{
  int blk = blockIdx.x;           // 16 rows: blk*16 .. blk*16+15
  int tid = threadIdx.x, lane = tid&63, w = tid>>6;
  int l15 = lane&15, lq = lane>>4;
  int b = blk >> 4;               // batch index (256 rows per b)
  int rr = ((blk & 15)*16) + l15; // rel index of this lane's row
  __shared__ __align__(16) bf16 Ah[16*256];   // 8KB h rows (bf16)

  f32x4 h[4];
  #pragma unroll
  for (int jq=0;jq<4;++jq) h[jq] = f32x4{0.f,0.f,0.f,0.f};

  for (int s=0; s<SEQQ; ++s){
    int t = time_idx[b*SEQQ + s];
    size_t gib = (size_t)(t*256 + rr)*768;
    f32x4 gh[12];
    #pragma unroll
    for (int ni=0;ni<12;++ni){
      int col = (ni>>2)*256 + w*64 + (ni&3)*16 + lq*4;
      gh[ni] = *(const f32x4*)(bhh + col);
    }
    if (s > 0){
      #pragma unroll
      for (int ks=0; ks<8; ++ks){
        bf16x8 a = *(const bf16x8*)(&Ah[0] + (size_t)l15*256 + ks*32 + lq*8);
        #pragma unroll
        for (int ni=0;ni<12;++ni){
          int n = (ni>>2)*256 + w*64 + (ni&3)*16 + l15;
          bf16x8 wv = *(const bf16x8*)(WhhT + (size_t)n*256 + ks*32 + lq*8);
          gh[ni] = __builtin_amdgcn_mfma_f32_16x16x32_bf16(wv, a, gh[ni], 0,0,0);
        }
      }
    }
    #pragma unroll
    for (int jq=0;jq<4;++jq){
      int col = w*64 + jq*16 + lq*4;
      f32x4 ir = *(const f32x4*)(GI + gib + col);
      f32x4 iz = *(const f32x4*)(GI + gib + 256 + col);
      f32x4 in = *(const f32x4*)(GI + gib + 512 + col);
      #pragma unroll
      for (int q=0;q<4;++q){
        float rg = 1.f/(1.f + __expf(-(ir[q] + gh[jq][q])));
        float zz = 1.f/(1.f + __expf(-(iz[q] + gh[4+jq][q])));
        float nn = tanhf(in[q] + rg*gh[8+jq][q]);
        h[jq][q] = (1.f - zz)*nn + zz*h[jq][q];
      }
    }
    if (s < SEQQ-1){
      __syncthreads();
      #pragma unroll
      for (int jq=0;jq<4;++jq){
        bf16x4 o;
        #pragma unroll
        for (int q=0;q<4;++q) o[q] = (bf16)h[jq][q];
        *(bf16x4*)(&Ah[0] + (size_t)l15*256 + w*64 + jq*16 + lq*4) = o;
      }
      __syncthreads();
    }
  }
  #pragma unroll
  for (int jq=0;jq<4;++jq){
    f32x4 o = h[jq];
    *(f32x4*)(out + (size_t)(blk*16 + l15)*256 + w*64 + jq*16 + lq*4) = o;
  }
}

// ---------------- launch ----------------
extern "C" void kernel_launch(void* const* d_in, const int* in_sizes, int n_in,
                              void* d_out, int out_size, void* d_ws, size_t ws_size,
                              hipStream_t stream)
{
  (void)in_sizes; (void)n_in; (void)out_size; (void)ws_size;
  const float* node_embeds = (const float*)d_in[0];
  const float* text_emb    = (const float*)d_in[1];
  const float* text_w_W    = (const float*)d_in[2];
  const float* text_w_b    = (const float*)d_in[3];
  const float* edge_w_W    = (const float*)d_in[4];
  const float* edge_w_b    = (const float*)d_in[5];
  const float* gru_Wih     = (const float*)d_in[6];
  const float* gru_Whh     = (const float*)d_in[7];
  const float* gru_bih     = (const float*)d_in[8];
  const float* gru_bhh     = (const float*)d_in[9];
  const int* edge_src      = (const int*)d_in[10];
  const int* edge_dst      = (const int*)d_in[11];
  const int* edge_rel      = (const int*)d_in[12];
  const int* time_idx      = (const int*)d_in[13];
  float* out = (float*)d_out;
  char* ws = (char*)d_ws;

  size_t o = 0;
  bf16*  WbT    = (bf16*) (ws + o); o += (size_t)768*256*2;
  bf16*  WihT   = (bf16*) (ws + o); o += (size_t)768*256*2;
  bf16*  WhhT   = (bf16*) (ws + o); o += (size_t)768*256*2;
  float* bfused = (float*)(ws + o); o += 1024;
  bf16*  node_bf= (bf16*) (ws + o); o += (size_t)NPAD*256*2;      // 25.6MB
  int*   counts = (int*)  (ws + o); o += (size_t)TT*256*4;
  int*   offs   = (int*)  (ws + o); o += (size_t)TT*256*4;
  int*   cursor = (int*)  (ws + o); o += (size_t)TT*256*4;
  int*   gperm  = (int*)  (ws + o); o += (size_t)TT*EE*4;
  int*   src_p  = (int*)  (ws + o); o += (size_t)TT*EE*4;
  int*   dst_p  = (int*)  (ws + o); o += (size_t)TT*EE*4;
  int*   tr_p   = (int*)  (ws + o); o += (size_t)TT*EE*4;
  bf16*  rel_bf = (bf16*) (ws + o); o += (size_t)TT*256*256*2;
  bf16*  P      = (bf16*) (ws + o); o += (size_t)NPAD*256*2;      // 25.6MB
  bf16*  Q      = (bf16*) (ws + o); o += (size_t)NPAD*256*2;      // 25.6MB
  float* rel_sum= (float*)(ws + o); o += (size_t)TT*256*256*4;    // 6.3MB
  float* GI     = (float*)(ws + o); o += (size_t)TT*256*768*4;    // 18.9MB
  bf16*  text_bp= (bf16*) (ws + o); o += (size_t)TT*EE*256*2;     // 245.8MB

  k_cvt8<<<6250,256,0,stream>>>(node_embeds, node_bf, NNODES*256/8);
  k_build_wbt<<<256,256,0,stream>>>(text_w_W, edge_w_W, WbT);
  k_bias<<<1,256,0,stream>>>(text_w_b, edge_w_W, edge_w_b, bfused);
  k_gruWT<<<768,256,0,stream>>>(gru_Wih, WihT);
  k_gruWT<<<768,256,0,stream>>>(gru_Whh, WhhT);
  k_hist<<<TT,256,0,stream>>>(edge_rel, counts, offs, cursor);
  k_perm<<<dim3((EE+255)/256,TT),256,0,stream>>>(edge_rel, edge_src, edge_dst,
                                                 cursor, gperm, src_p, dst_p, tr_p);
  k_projn<<<NPAD/128,256,0,stream>>>(node_bf, WbT, 0,   P);
  k_projn<<<NPAD/128,256,0,stream>>>(node_bf, WbT, 512, Q);
  k_textp<<<TT*EE/4,256,0,stream>>>(text_emb, gperm, text_bp);
  hipMemsetAsync(rel_sum, 0, (size_t)TT*256*256*4, stream);
  k_projtc<<<TT*EE/64,256,0,stream>>>(text_bp, WbT, bfused, P, Q,
                                      src_p, dst_p, tr_p, rel_sum);
  k_mean<<<TT*256,256,0,stream>>>(rel_sum, counts, rel_bf);
  // GI = rel_emb @ Wih + bih  (M=6144)
  k_gemm<<<dim3(48,6),256,0,stream>>>(rel_bf, WihT, gru_bih, GI);
  // whole GRU sequence in one kernel
  k_gru<<<256,256,0,stream>>>(GI, WhhT, gru_bhh, time_idx, out);
}

// Round 18
// 576.967 us; speedup vs baseline: 1.1178x; 1.1178x over previous
//
#include <hip/hip_runtime.h>
#include <cstdint>
#include <cstddef>

#define NNODES 50000
#define NPAD   50048        // 391*128, padded M for P/Q GEMM
#define NRELS  256
#define DIM    256
#define TT     24
#define EE     20000
#define BATCH  16
#define SEQQ   7

typedef __bf16 bf16;
typedef __bf16 bf16x4 __attribute__((ext_vector_type(4)));
typedef __bf16 bf16x8 __attribute__((ext_vector_type(8)));
typedef float  f32x4  __attribute__((ext_vector_type(4)));

// async global->LDS, 16B per lane; LDS dest is wave-uniform base (+lane*16 by HW);
// the GLOBAL source address is per-lane (m173).
__device__ __forceinline__ void gload16(const void* g, void* l){
  __builtin_amdgcn_global_load_lds((const __attribute__((address_space(1))) void*)g,
                                   (__attribute__((address_space(3))) void*)l, 16, 0, 0);
}

// ---------------- prep kernels ----------------

__global__ void k_cvt8(const float* __restrict__ in, bf16* __restrict__ out, int n8){
  int i = blockIdx.x*256 + threadIdx.x;
  if (i >= n8) return;
  const float4* p = (const float4*)in + (size_t)i*2;
  float4 a = p[0], b = p[1];
  bf16x8 o;
  o[0]=(bf16)a.x; o[1]=(bf16)a.y; o[2]=(bf16)a.z; o[3]=(bf16)a.w;
  o[4]=(bf16)b.x; o[5]=(bf16)b.y; o[6]=(bf16)b.z; o[7]=(bf16)b.w;
  ((bf16x8*)out)[i] = o;
}

// Fused edge weight, transposed: WbT[n][k], k in [0,768) = [W1 | W2fold | W3].
__global__ void k_build_wbt(const float* __restrict__ tW, const float* __restrict__ eW,
                            bf16* __restrict__ WbT){
  int n = blockIdx.x, j = threadIdx.x;
  WbT[(size_t)n*768 + j]       = (bf16)eW[(size_t)j*256 + n];
  WbT[(size_t)n*768 + 512 + j] = (bf16)eW[(size_t)(512+j)*256 + n];
  float acc = 0.f;
  for (int m=0; m<256; ++m) acc += tW[(size_t)j*256 + m] * eW[(size_t)(256+m)*256 + n];
  WbT[(size_t)n*768 + 256 + j] = (bf16)acc;
}

// fused bias: bfused[n] = edge_w_b[n] + sum_m text_w_b[m]*W2[m][n]
__global__ void k_bias(const float* __restrict__ tb, const float* __restrict__ eW,
                       const float* __restrict__ eb, float* __restrict__ bf){
  int n = threadIdx.x;
  float acc = eb[n];
  for (int m=0; m<256; ++m) acc += tb[m] * eW[(size_t)(256+m)*256 + n];
  bf[n] = acc;
}

// gru weight [256][768] -> transposed bf16 [768][256]
__global__ void k_gruWT(const float* __restrict__ W, bf16* __restrict__ WT){
  int n = blockIdx.x, k = threadIdx.x;
  WT[(size_t)n*256 + k] = (bf16)W[(size_t)k*768 + n];
}

// per-t histogram of rels + exclusive scan
__global__ void k_hist(const int* __restrict__ rel, int* __restrict__ counts,
                       int* __restrict__ offs, int* __restrict__ cursor){
  __shared__ int hist[256];
  __shared__ int scan[256];
  int t = blockIdx.x, tid = threadIdx.x;
  hist[tid] = 0;
  __syncthreads();
  for (int e = tid; e < EE; e += 256) atomicAdd(&hist[rel[(size_t)t*EE + e]], 1);
  __syncthreads();
  int v = hist[tid];
  scan[tid] = v;
  __syncthreads();
  for (int d=1; d<256; d<<=1){
    int add = (tid >= d) ? scan[tid-d] : 0;
    __syncthreads();
    scan[tid] += add;
    __syncthreads();
  }
  int ex = scan[tid] - v;
  counts[t*256+tid] = v;
  offs[t*256+tid]   = ex;
  cursor[t*256+tid] = ex;
}

// bucket edges by (t,rel): emit global text row index and src/dst ids
__global__ void k_perm(const int* __restrict__ rel, const int* __restrict__ esrc,
                       const int* __restrict__ edst, int* __restrict__ cursor,
                       int* __restrict__ gperm, int* __restrict__ src_p,
                       int* __restrict__ dst_p){
  int t = blockIdx.y;
  int e = blockIdx.x*256 + threadIdx.x;
  if (e < EE){
    int r = rel[(size_t)t*EE + e];
    int p = atomicAdd(&cursor[t*256 + r], 1);
    size_t g = (size_t)t*EE + p;
    gperm[g] = t*EE + e;
    src_p[g] = esrc[(size_t)t*EE + e];
    dst_p[g] = edst[(size_t)t*EE + e];
  }
}

// ---------------- node projection GEMM (swapped operands, coalesced stores) ----
__global__ __launch_bounds__(256) void k_projn(
    const bf16* __restrict__ Abf, const bf16* __restrict__ WbT, int koff,
    bf16* __restrict__ out)
{
  int m0 = blockIdx.x*128;
  int tid = threadIdx.x, lane = tid&63, w = tid>>6;
  int l15 = lane&15, lq = lane>>4;
  int c0 = w*64;
  __shared__ __align__(16) bf16 Al[128*32];   // 8KB
  __shared__ __align__(16) bf16 Bl[256*32];   // 16KB

  f32x4 acc[8][4];
  f32x4 z4 = {0.f,0.f,0.f,0.f};
  #pragma unroll
  for (int mi=0;mi<8;++mi)
    #pragma unroll
    for (int ni=0;ni<4;++ni) acc[mi][ni]=z4;

  for (int ks=0; ks<8; ++ks){
    int k0 = ks*32;
    #pragma unroll
    for (int p=0;p<2;++p){
      int c = p*256 + tid;
      int rw = c>>2, prt = c&3;
      int pp = prt ^ ((rw>>1)&3);
      const char* src = (const char*)(Abf + (size_t)(m0+rw)*256 + k0) + pp*16;
      gload16(src, (char*)Al + (size_t)(p*256 + w*64)*16);
    }
    #pragma unroll
    for (int p=0;p<4;++p){
      int c = p*256 + tid;
      int nn = c>>2, prt = c&3;
      int pp = prt ^ ((nn>>1)&3);
      const char* src = (const char*)(WbT + (size_t)nn*768 + koff + k0) + pp*16;
      gload16(src, (char*)Bl + (size_t)(p*256 + w*64)*16);
    }
    __syncthreads();
    bf16x8 b[4];
    #pragma unroll
    for (int ni=0;ni<4;++ni){
      int nn = c0 + ni*16 + l15;
      b[ni] = *(const bf16x8*)((const char*)Bl + (size_t)nn*64 + (size_t)((lq ^ ((nn>>1)&3))*16));
    }
    #pragma unroll
    for (int mi=0;mi<8;++mi){
      int rw = mi*16 + l15;
      bf16x8 a = *(const bf16x8*)((const char*)Al + (size_t)rw*64 + (size_t)((lq ^ ((rw>>1)&3))*16));
      #pragma unroll
      for (int ni=0;ni<4;++ni)
        acc[mi][ni] = __builtin_amdgcn_mfma_f32_16x16x32_bf16(b[ni], a, acc[mi][ni], 0,0,0);
    }
    __syncthreads();
  }
  #pragma unroll
  for (int mi=0;mi<8;++mi){
    int row = m0 + mi*16 + l15;
    #pragma unroll
    for (int ni=0;ni<4;++ni){
      bf16x4 o;
      #pragma unroll
      for (int q=0;q<4;++q) o[q] = (bf16)acc[mi][ni][q];
      *(bf16x4*)(out + (size_t)row*256 + c0 + ni*16 + lq*4) = o;
    }
  }
}

// ---- text projection in NATURAL order: T[e] = text[e] @ W2fold ----
// Pure sequential fp32 read (64KB tile staged whole via gload16, 16/thread),
// one barrier, zero-barrier MFMA loop (r16-verified swizzle), sequential
// bf16 write. No gather anywhere: DRAM sees only streams.
// Swizzle (both-sides): LDS slot s of row r holds source part
// (s&56)|((s^r)&7); reader of part p=ks*8+lq*2+j at row rw uses slot
// ks*8 + ((lq*2+j)^(rw&7)) -> 2-way banks (free).
__global__ __launch_bounds__(256,2) void k_projt(
    const float* __restrict__ text, const bf16* __restrict__ WbT,
    bf16* __restrict__ out)
{
  int m0 = blockIdx.x*64;
  int tid = threadIdx.x, lane = tid&63, w = tid>>6;
  int l15 = lane&15, lq = lane>>4;
  int c0 = w*64;
  __shared__ __align__(16) float Afl[64*256];    // 64KB fp32 tile

  // stage whole tile: wave w, instruction i stages row ri = i*4+w (sequential)
  #pragma unroll
  for (int i=0;i<16;++i){
    int ri = i*4 + w;
    int sp = (lane & 56) | ((lane ^ ri) & 7);
    const float* src = text + (size_t)(m0 + ri)*256 + sp*4;
    gload16(src, (char*)Afl + (size_t)(i*256 + w*64)*16);
  }
  __syncthreads();

  const bf16* bBase = WbT + (size_t)(c0 + l15)*768 + 256 + lq*8;

  f32x4 acc[4][4];
  f32x4 z4 = {0.f,0.f,0.f,0.f};
  #pragma unroll
  for (int mi=0;mi<4;++mi)
    #pragma unroll
    for (int ni=0;ni<4;++ni) acc[mi][ni]=z4;

  #pragma unroll
  for (int ks=0; ks<8; ++ks){
    bf16x8 b[4];
    #pragma unroll
    for (int ni=0;ni<4;++ni)
      b[ni] = *(const bf16x8*)(bBase + (size_t)ni*16*768 + ks*32);
    bf16x8 a[4];
    #pragma unroll
    for (int mi=0;mi<4;++mi){
      int rw = mi*16 + l15;
      int s7 = rw & 7;
      const char* ab = (const char*)Afl + (size_t)rw*1024 + (size_t)ks*128;
      f32x4 f0 = *(const f32x4*)(ab + (size_t)(((lq*2+0)^s7))*16);
      f32x4 f1 = *(const f32x4*)(ab + (size_t)(((lq*2+1)^s7))*16);
      bf16x8 o;
      o[0]=(bf16)f0[0]; o[1]=(bf16)f0[1]; o[2]=(bf16)f0[2]; o[3]=(bf16)f0[3];
      o[4]=(bf16)f1[0]; o[5]=(bf16)f1[1]; o[6]=(bf16)f1[2]; o[7]=(bf16)f1[3];
      a[mi] = o;
    }
    #pragma unroll
    for (int mi=0;mi<4;++mi)
      #pragma unroll
      for (int ni=0;ni<4;++ni)
        acc[mi][ni] = __builtin_amdgcn_mfma_f32_16x16x32_bf16(b[ni], a[mi], acc[mi][ni], 0,0,0);
  }

  #pragma unroll
  for (int mi=0;mi<4;++mi){
    int row = m0 + mi*16 + l15;
    #pragma unroll
    for (int ni=0;ni<4;++ni){
      bf16x4 o;
      #pragma unroll
      for (int q=0;q<4;++q) o[q] = (bf16)acc[mi][ni][q];
      *(bf16x4*)(out + (size_t)row*256 + c0 + ni*16 + lq*4) = o;
    }
  }
}

// ---------------- combine: gather P/Q/T(+perm) + bias + relu + segment mean ----
// One block per (t,rel). 8 edge slots x 32 col-threads (8 cols each).
// T is gathered via gperm (random 512B bf16 rows; Tproj just written, mostly
// L3-resident). No barriers in the loop; one LDS reduce; direct rel_bf write.
__global__ __launch_bounds__(256) void k_comb(
    const bf16* __restrict__ P, const bf16* __restrict__ Q,
    const bf16* __restrict__ T, const float* __restrict__ bfused,
    const int* __restrict__ gperm,
    const int* __restrict__ src_p, const int* __restrict__ dst_p,
    const int* __restrict__ counts, const int* __restrict__ offs,
    bf16* __restrict__ rel_bf)
{
  int r = blockIdx.x, t = blockIdx.y;
  int tid = threadIdx.x;
  int tr = t*256 + r;
  int nE = counts[tr];
  if (nE == 0){
    rel_bf[(size_t)tr*256 + tid] = (bf16)0.f;
    return;
  }
  int base = offs[tr];
  int es = tid>>5, cg = (tid&31)*8;
  float bb[8];
  {
    float4 b0 = *(const float4*)(bfused + cg);
    float4 b1 = *(const float4*)(bfused + cg + 4);
    bb[0]=b0.x; bb[1]=b0.y; bb[2]=b0.z; bb[3]=b0.w;
    bb[4]=b1.x; bb[5]=b1.y; bb[6]=b1.z; bb[7]=b1.w;
  }
  float acc[8];
  #pragma unroll
  for (int j=0;j<8;++j) acc[j]=0.f;
  for (int i = es; i < nE; i += 8){
    size_t g = (size_t)t*EE + base + i;
    int s = src_p[g], d = dst_p[g];
    int e = gperm[g];
    bf16x8 pv = *(const bf16x8*)(P + (size_t)s*256 + cg);
    bf16x8 qv = *(const bf16x8*)(Q + (size_t)d*256 + cg);
    bf16x8 tv = *(const bf16x8*)(T + (size_t)e*256 + cg);
    #pragma unroll
    for (int j=0;j<8;++j)
      acc[j] += fmaxf((float)pv[j] + (float)qv[j] + (float)tv[j] + bb[j], 0.f);
  }
  __shared__ float red[8][256];
  #pragma unroll
  for (int j=0;j<8;++j) red[es][cg+j] = acc[j];
  __syncthreads();
  float s = 0.f;
  #pragma unroll
  for (int e=0;e<8;++e) s += red[e][tid];
  rel_bf[(size_t)tr*256 + tid] = (bf16)(s / (float)nE);
}

// ---------------- plain bf16 GEMM (GI), K=256, out f32 stride 768 ----------------
__global__ __launch_bounds__(256) void k_gemm(
    const bf16* __restrict__ A, const bf16* __restrict__ BT,
    const float* __restrict__ bias, float* __restrict__ Out)
{
  int m0 = blockIdx.x*128, n0 = blockIdx.y*128;
  int tid = threadIdx.x, lane = tid&63, w = tid>>6;
  int l15 = lane&15, lq = lane>>4;
  __shared__ __align__(16) bf16 Al[128*32];
  __shared__ __align__(16) bf16 Bl[128*32];
  int wr = (w&1)*64, wc = (w>>1)*64;
  f32x4 acc[4][4];
  f32x4 z4 = {0.f,0.f,0.f,0.f};
  #pragma unroll
  for (int mi=0;mi<4;++mi)
    #pragma unroll
    for (int ni=0;ni<4;++ni) acc[mi][ni]=z4;
  for (int ks=0; ks<8; ++ks){
    int k0 = ks*32;
    #pragma unroll
    for (int p=0;p<2;++p){
      int c = p*256 + tid;
      int rw = c>>2, part = c&3;
      int pp = part ^ ((rw>>1)&3);
      const char* src = (const char*)(A + (size_t)(m0+rw)*256 + k0) + pp*16;
      gload16(src, (char*)Al + (size_t)(p*256 + w*64)*16);
    }
    #pragma unroll
    for (int p=0;p<2;++p){
      int c = p*256 + tid;
      int nn = c>>2, part = c&3;
      int pp = part ^ ((nn>>1)&3);
      const char* src = (const char*)(BT + (size_t)(n0+nn)*256 + k0) + pp*16;
      gload16(src, (char*)Bl + (size_t)(p*256 + w*64)*16);
    }
    __syncthreads();
    bf16x8 a[4], b[4];
    #pragma unroll
    for (int mi=0;mi<4;++mi){
      int rw = wr + mi*16 + l15;
      a[mi] = *(const bf16x8*)((const char*)Al + (size_t)rw*64 + (size_t)((lq ^ ((rw>>1)&3))*16));
    }
    #pragma unroll
    for (int ni=0;ni<4;++ni){
      int nn = wc + ni*16 + l15;
      b[ni] = *(const bf16x8*)((const char*)Bl + (size_t)nn*64 + (size_t)((lq ^ ((nn>>1)&3))*16));
    }
    #pragma unroll
    for (int mi=0;mi<4;++mi)
      #pragma unroll
      for (int ni=0;ni<4;++ni)
        acc[mi][ni] = __builtin_amdgcn_mfma_f32_16x16x32_bf16(a[mi], b[ni], acc[mi][ni], 0,0,0);
    __syncthreads();
  }
  #pragma unroll
  for (int ni=0;ni<4;++ni){
    int col = n0 + wc + ni*16 + l15;
    float bv = bias[col];
    #pragma unroll
    for (int mi=0;mi<4;++mi){
      #pragma unroll
      for (int q=0;q<4;++q){
        int row = m0 + wr + mi*16 + lq*4 + q;
        Out[(size_t)row*768 + col] = acc[mi][ni][q] + bv;
      }
    }
  }
}

// ---------------- fused whole-sequence GRU ----------------
__global__ __launch_bounds__(256) void k_gru(
    const float* __restrict__ GI, const bf16* __restrict__ WhhT,
    const float* __restrict__ bhh, const int* __restrict__ time_idx,
    float* __restrict__ out)
{
  int blk = blockIdx.x;           // 16 rows: blk*16 .. blk*16+15
  int tid = threadIdx.x, lane = tid&63, w = tid>>6;
  int l15 = lane&15, lq = lane>>4;
  int b = blk >> 4;               // batch index (256 rows per b)
  int rr = ((blk & 15)*16) + l15; // rel index of this lane's row
  __shared__ __align__(16) bf16 Ah[16*256];   // 8KB h rows (bf16)

  f32x4 h[4];
  #pragma unroll
  for (int jq=0;jq<4;++jq) h[jq] = f32x4{0.f,0.f,0.f,0.f};

  for (int s=0; s<SEQQ; ++s){
    int t = time_idx[b*SEQQ + s];
    size_t gib = (size_t)(t*256 + rr)*768;
    f32x4 gh[12];
    #pragma unroll
    for (int ni=0;ni<12;++ni){
      int col = (ni>>2)*256 + w*64 + (ni&3)*16 + lq*4;
      gh[ni] = *(const f32x4*)(bhh + col);
    }
    if (s > 0){
      #pragma unroll
      for (int ks=0; ks<8; ++ks){
        bf16x8 a = *(const bf16x8*)(&Ah[0] + (size_t)l15*256 + ks*32 + lq*8);
        #pragma unroll
        for (int ni=0;ni<12;++ni){
          int n = (ni>>2)*256 + w*64 + (ni&3)*16 + l15;
          bf16x8 wv = *(const bf16x8*)(WhhT + (size_t)n*256 + ks*32 + lq*8);
          gh[ni] = __builtin_amdgcn_mfma_f32_16x16x32_bf16(wv, a, gh[ni], 0,0,0);
        }
      }
    }
    #pragma unroll
    for (int jq=0;jq<4;++jq){
      int col = w*64 + jq*16 + lq*4;
      f32x4 ir = *(const f32x4*)(GI + gib + col);
      f32x4 iz = *(const f32x4*)(GI + gib + 256 + col);
      f32x4 in = *(const f32x4*)(GI + gib + 512 + col);
      #pragma unroll
      for (int q=0;q<4;++q){
        float rg = 1.f/(1.f + __expf(-(ir[q] + gh[jq][q])));
        float zz = 1.f/(1.f + __expf(-(iz[q] + gh[4+jq][q])));
        float nn = tanhf(in[q] + rg*gh[8+jq][q]);
        h[jq][q] = (1.f - zz)*nn + zz*h[jq][q];
      }
    }
    if (s < SEQQ-1){
      __syncthreads();
      #pragma unroll
      for (int jq=0;jq<4;++jq){
        bf16x4 o;
        #pragma unroll
        for (int q=0;q<4;++q) o[q] = (bf16)h[jq][q];
        *(bf16x4*)(&Ah[0] + (size_t)l15*256 + w*64 + jq*16 + lq*4) = o;
      }
      __syncthreads();
    }
  }
  #pragma unroll
  for (int jq=0;jq<4;++jq){
    f32x4 o = h[jq];
    *(f32x4*)(out + (size_t)(blk*16 + l15)*256 + w*64 + jq*16 + lq*4) = o;
  }
}

// ---------------- launch ----------------
extern "C" void kernel_launch(void* const* d_in, const int* in_sizes, int n_in,
                              void* d_out, int out_size, void* d_ws, size_t ws_size,
                              hipStream_t stream)
{
  (void)in_sizes; (void)n_in; (void)out_size; (void)ws_size;
  const float* node_embeds = (const float*)d_in[0];
  const float* text_emb    = (const float*)d_in[1];
  const float* text_w_W    = (const float*)d_in[2];
  const float* text_w_b    = (const float*)d_in[3];
  const float* edge_w_W    = (const float*)d_in[4];
  const float* edge_w_b    = (const float*)d_in[5];
  const float* gru_Wih     = (const float*)d_in[6];
  const float* gru_Whh     = (const float*)d_in[7];
  const float* gru_bih     = (const float*)d_in[8];
  const float* gru_bhh     = (const float*)d_in[9];
  const int* edge_src      = (const int*)d_in[10];
  const int* edge_dst      = (const int*)d_in[11];
  const int* edge_rel      = (const int*)d_in[12];
  const int* time_idx      = (const int*)d_in[13];
  float* out = (float*)d_out;
  char* ws = (char*)d_ws;

  size_t o = 0;
  bf16*  WbT    = (bf16*) (ws + o); o += (size_t)768*256*2;
  bf16*  WihT   = (bf16*) (ws + o); o += (size_t)768*256*2;
  bf16*  WhhT   = (bf16*) (ws + o); o += (size_t)768*256*2;
  float* bfused = (float*)(ws + o); o += 1024;
  bf16*  node_bf= (bf16*) (ws + o); o += (size_t)NPAD*256*2;      // 25.6MB
  int*   counts = (int*)  (ws + o); o += (size_t)TT*256*4;
  int*   offs   = (int*)  (ws + o); o += (size_t)TT*256*4;
  int*   cursor = (int*)  (ws + o); o += (size_t)TT*256*4;
  int*   gperm  = (int*)  (ws + o); o += (size_t)TT*EE*4;
  int*   src_p  = (int*)  (ws + o); o += (size_t)TT*EE*4;
  int*   dst_p  = (int*)  (ws + o); o += (size_t)TT*EE*4;
  bf16*  rel_bf = (bf16*) (ws + o); o += (size_t)TT*256*256*2;
  bf16*  P      = (bf16*) (ws + o); o += (size_t)NPAD*256*2;      // 25.6MB
  bf16*  Q      = (bf16*) (ws + o); o += (size_t)NPAD*256*2;      // 25.6MB
  float* GI     = (float*)(ws + o); o += (size_t)TT*256*768*4;    // 18.9MB
  bf16*  Tproj  = (bf16*) (ws + o); o += (size_t)TT*EE*256*2;     // 245.8MB (natural order)

  k_cvt8<<<6250,256,0,stream>>>(node_embeds, node_bf, NNODES*256/8);
  k_build_wbt<<<256,256,0,stream>>>(text_w_W, edge_w_W, WbT);
  k_bias<<<1,256,0,stream>>>(text_w_b, edge_w_W, edge_w_b, bfused);
  k_gruWT<<<768,256,0,stream>>>(gru_Wih, WihT);
  k_gruWT<<<768,256,0,stream>>>(gru_Whh, WhhT);
  k_hist<<<TT,256,0,stream>>>(edge_rel, counts, offs, cursor);
  k_perm<<<dim3((EE+255)/256,TT),256,0,stream>>>(edge_rel, edge_src, edge_dst,
                                                 cursor, gperm, src_p, dst_p);
  k_projn<<<NPAD/128,256,0,stream>>>(node_bf, WbT, 0,   P);
  k_projn<<<NPAD/128,256,0,stream>>>(node_bf, WbT, 512, Q);
  // natural-order text projection: pure streams, no gather
  k_projt<<<TT*EE/64,256,0,stream>>>(text_emb, WbT, Tproj);
  // combine gathers the (smaller, bf16, L3-warm) T rows instead of fp32 text
  k_comb<<<dim3(256,TT),256,0,stream>>>(P, Q, Tproj, bfused, gperm,
                                        src_p, dst_p, counts, offs, rel_bf);
  // GI = rel_emb @ Wih + bih  (M=6144)
  k_gemm<<<dim3(48,6),256,0,stream>>>(rel_bf, WihT, gru_bih, GI);
  // whole GRU sequence in one kernel
  k_gru<<<256,256,0,stream>>>(GI, WhhT, gru_bhh, time_idx, out);
}

// Round 19
// 538.528 us; speedup vs baseline: 1.1976x; 1.0714x over previous
//
#include <hip/hip_runtime.h>
#include <cstdint>
#include <cstddef>

#define NNODES 50000
#define NPAD   50048        // 391*128, padded M for P/Q GEMM
#define NRELS  256
#define DIM    256
#define TT     24
#define EE     20000
#define BATCH  16
#define SEQQ   7

typedef __bf16 bf16;
typedef __bf16 bf16x4 __attribute__((ext_vector_type(4)));
typedef __bf16 bf16x8 __attribute__((ext_vector_type(8)));
typedef float  f32x4  __attribute__((ext_vector_type(4)));

// async global->LDS, 16B per lane; LDS dest is wave-uniform base (+lane*16 by HW);
// the GLOBAL source address is per-lane (m173) -> per-row gathers are fine.
__device__ __forceinline__ void gload16(const void* g, void* l){
  __builtin_amdgcn_global_load_lds((const __attribute__((address_space(1))) void*)g,
                                   (__attribute__((address_space(3))) void*)l, 16, 0, 0);
}

// ---------------- prep kernels ----------------

__global__ void k_cvt8(const float* __restrict__ in, bf16* __restrict__ out, int n8){
  int i = blockIdx.x*256 + threadIdx.x;
  if (i >= n8) return;
  const float4* p = (const float4*)in + (size_t)i*2;
  float4 a = p[0], b = p[1];
  bf16x8 o;
  o[0]=(bf16)a.x; o[1]=(bf16)a.y; o[2]=(bf16)a.z; o[3]=(bf16)a.w;
  o[4]=(bf16)b.x; o[5]=(bf16)b.y; o[6]=(bf16)b.z; o[7]=(bf16)b.w;
  ((bf16x8*)out)[i] = o;
}

// Fused edge weight, transposed: WbT[n][k], k in [0,768) = [W1 | W2fold | W3].
__global__ void k_build_wbt(const float* __restrict__ tW, const float* __restrict__ eW,
                            bf16* __restrict__ WbT){
  int n = blockIdx.x, j = threadIdx.x;
  WbT[(size_t)n*768 + j]       = (bf16)eW[(size_t)j*256 + n];
  WbT[(size_t)n*768 + 512 + j] = (bf16)eW[(size_t)(512+j)*256 + n];
  float acc = 0.f;
  for (int m=0; m<256; ++m) acc += tW[(size_t)j*256 + m] * eW[(size_t)(256+m)*256 + n];
  WbT[(size_t)n*768 + 256 + j] = (bf16)acc;
}

// fused bias: bfused[n] = edge_w_b[n] + sum_m text_w_b[m]*W2[m][n]
__global__ void k_bias(const float* __restrict__ tb, const float* __restrict__ eW,
                       const float* __restrict__ eb, float* __restrict__ bf){
  int n = threadIdx.x;
  float acc = eb[n];
  for (int m=0; m<256; ++m) acc += tb[m] * eW[(size_t)(256+m)*256 + n];
  bf[n] = acc;
}

// gru weight [256][768] -> transposed bf16 [768][256]
__global__ void k_gruWT(const float* __restrict__ W, bf16* __restrict__ WT){
  int n = blockIdx.x, k = threadIdx.x;
  WT[(size_t)n*256 + k] = (bf16)W[(size_t)k*768 + n];
}

// per-t histogram of rels + exclusive scan
__global__ void k_hist(const int* __restrict__ rel, int* __restrict__ counts,
                       int* __restrict__ offs, int* __restrict__ cursor){
  __shared__ int hist[256];
  __shared__ int scan[256];
  int t = blockIdx.x, tid = threadIdx.x;
  hist[tid] = 0;
  __syncthreads();
  for (int e = tid; e < EE; e += 256) atomicAdd(&hist[rel[(size_t)t*EE + e]], 1);
  __syncthreads();
  int v = hist[tid];
  scan[tid] = v;
  __syncthreads();
  for (int d=1; d<256; d<<=1){
    int add = (tid >= d) ? scan[tid-d] : 0;
    __syncthreads();
    scan[tid] += add;
    __syncthreads();
  }
  int ex = scan[tid] - v;
  counts[t*256+tid] = v;
  offs[t*256+tid]   = ex;
  cursor[t*256+tid] = ex;
}

// bucket edges by (t,rel): emit global text row index, src/dst ids, and tr id
__global__ void k_perm(const int* __restrict__ rel, const int* __restrict__ esrc,
                       const int* __restrict__ edst, int* __restrict__ cursor,
                       int* __restrict__ gperm, int* __restrict__ src_p,
                       int* __restrict__ dst_p, int* __restrict__ tr_p){
  int t = blockIdx.y;
  int e = blockIdx.x*256 + threadIdx.x;
  if (e < EE){
    int r = rel[(size_t)t*EE + e];
    int p = atomicAdd(&cursor[t*256 + r], 1);
    size_t g = (size_t)t*EE + p;
    gperm[g] = t*EE + e;
    src_p[g] = esrc[(size_t)t*EE + e];
    dst_p[g] = edst[(size_t)t*EE + e];
    tr_p[g]  = t*256 + r;
  }
}

// ---------------- node projection GEMM (swapped operands, coalesced stores) ----
__global__ __launch_bounds__(256) void k_projn(
    const bf16* __restrict__ Abf, const bf16* __restrict__ WbT, int koff,
    bf16* __restrict__ out)
{
  int m0 = blockIdx.x*128;
  int tid = threadIdx.x, lane = tid&63, w = tid>>6;
  int l15 = lane&15, lq = lane>>4;
  int c0 = w*64;
  __shared__ __align__(16) bf16 Al[128*32];   // 8KB
  __shared__ __align__(16) bf16 Bl[256*32];   // 16KB

  f32x4 acc[8][4];
  f32x4 z4 = {0.f,0.f,0.f,0.f};
  #pragma unroll
  for (int mi=0;mi<8;++mi)
    #pragma unroll
    for (int ni=0;ni<4;++ni) acc[mi][ni]=z4;

  for (int ks=0; ks<8; ++ks){
    int k0 = ks*32;
    #pragma unroll
    for (int p=0;p<2;++p){
      int c = p*256 + tid;
      int rw = c>>2, prt = c&3;
      int pp = prt ^ ((rw>>1)&3);
      const char* src = (const char*)(Abf + (size_t)(m0+rw)*256 + k0) + pp*16;
      gload16(src, (char*)Al + (size_t)(p*256 + w*64)*16);
    }
    #pragma unroll
    for (int p=0;p<4;++p){
      int c = p*256 + tid;
      int nn = c>>2, prt = c&3;
      int pp = prt ^ ((nn>>1)&3);
      const char* src = (const char*)(WbT + (size_t)nn*768 + koff + k0) + pp*16;
      gload16(src, (char*)Bl + (size_t)(p*256 + w*64)*16);
    }
    __syncthreads();
    bf16x8 b[4];
    #pragma unroll
    for (int ni=0;ni<4;++ni){
      int nn = c0 + ni*16 + l15;
      b[ni] = *(const bf16x8*)((const char*)Bl + (size_t)nn*64 + (size_t)((lq ^ ((nn>>1)&3))*16));
    }
    #pragma unroll
    for (int mi=0;mi<8;++mi){
      int rw = mi*16 + l15;
      bf16x8 a = *(const bf16x8*)((const char*)Al + (size_t)rw*64 + (size_t)((lq ^ ((rw>>1)&3))*16));
      #pragma unroll
      for (int ni=0;ni<4;++ni)
        acc[mi][ni] = __builtin_amdgcn_mfma_f32_16x16x32_bf16(b[ni], a, acc[mi][ni], 0,0,0);
    }
    __syncthreads();
  }
  #pragma unroll
  for (int mi=0;mi<8;++mi){
    int row = m0 + mi*16 + l15;
    #pragma unroll
    for (int ni=0;ni<4;++ni){
      bf16x4 o;
      #pragma unroll
      for (int q=0;q<4;++q) o[q] = (bf16)acc[mi][ni][q];
      *(bf16x4*)(out + (size_t)row*256 + c0 + ni*16 + lq*4) = o;
    }
  }
}

// ---- fused text projection + gather-add-relu + segment-sum (r13 pipe + r6 epilogue) ----
// Per 64 sorted edge rows: T-row = text[gperm]@W2fold via the all-gload_lds
// counted-vmcnt pipeline; epilogue adds P[src]+Q[dst]+bfused, relu in place,
// then per (t,rel) run: masked mi-sum + shfl_xor butterfly over l15 + one
// atomicAdd per lane into fp32 rel_sum.
// Lane layout (swapped mfma, r6-verified): row = mi*16+l15,
// cols = c0 + ni*16 + lq*4 + {0..3}.
__global__ __launch_bounds__(256,3) void k_projtc(
    const float* __restrict__ text, const int* __restrict__ gperm,
    const bf16* __restrict__ WbT, const float* __restrict__ bfused,
    const bf16* __restrict__ P, const bf16* __restrict__ Q,
    const int* __restrict__ src_p, const int* __restrict__ dst_p,
    const int* __restrict__ tr_p, float* __restrict__ rel_sum)
{
  int m0 = blockIdx.x*64;
  int tid = threadIdx.x, lane = tid&63, w = tid>>6;
  int l15 = lane&15, lq = lane>>4;
  int c0 = w*64;
  __shared__ __align__(16) float Afl[2][64*32];  // 2 x 8KB fp32
  __shared__ __align__(16) bf16  Bl[2][256*32];  // 2 x 16KB
  __shared__ int trA[64], sIl[64], dIl[64];
  __shared__ int runS[65], runT[64];
  __shared__ int nRunS;

  if (tid < 64){
    int g = m0 + tid;
    trA[tid] = tr_p[g];
    sIl[tid] = src_p[g];
    dIl[tid] = dst_p[g];
  }
  __syncthreads();
  if (tid == 0){
    int nR = 0;
    for (int i=0;i<64;++i){
      if (i==0 || trA[i]!=trA[i-1]){ runS[nR]=i; runT[nR]=trA[i]; ++nR; }
    }
    runS[nR] = 64;
    nRunS = nR;
  }
  // (visibility: tid0's ds_writes drain at its first in-loop lgkmcnt(0);
  //  epilogue reads happen after many subsequent barriers)

  // A staging: thread handles chunks c=tid (row tid>>3) and c=256+tid (row 32+(tid>>3)),
  // part = tid&7; swizzled source part pp = part ^ (row&7) (same for both rows).
  int rA0 = tid>>3;
  int partA = tid&7;
  int ppA = partA ^ (rA0 & 7);
  const float* aPtr0 = text + (size_t)gperm[m0 + rA0]*256      + ppA*4;
  const float* aPtr1 = text + (size_t)gperm[m0 + 32 + rA0]*256 + ppA*4;

#define STAGEA(KS, BI)                                                        \
  { gload16(aPtr0 + (KS)*32, (char*)&Afl[BI][0] + (size_t)(w*64)*16);         \
    gload16(aPtr1 + (KS)*32, (char*)&Afl[BI][0] + (size_t)(256 + w*64)*16); }

#define STAGEB(KS, BI)                                                        \
  { _Pragma("unroll")                                                         \
    for (int p_=0;p_<4;++p_){                                                 \
      int c_ = p_*256 + tid;                                                  \
      int nn_ = c_>>2, prt_ = c_&3;                                           \
      int pp_ = prt_ ^ ((nn_>>1)&3);                                          \
      const char* src_ = (const char*)(WbT + (size_t)nn_*768 + 256 + (KS)*32) + pp_*16; \
      gload16(src_, (char*)&Bl[BI][0] + (size_t)(p_*256 + w*64)*16); } }

  f32x4 acc[4][4];
  f32x4 z4 = {0.f,0.f,0.f,0.f};
  #pragma unroll
  for (int mi=0;mi<4;++mi)
    #pragma unroll
    for (int ni=0;ni<4;++ni) acc[mi][ni]=z4;

  // prologue: stage step 0 into buf 0 (6 loads in flight)
  STAGEA(0, 0);
  STAGEB(0, 0);

  #pragma unroll
  for (int ks=0; ks<8; ++ks){
    const int bi = ks & 1;
    if (ks < 7){
      STAGEA(ks+1, bi^1);   // +2 VMEM
      STAGEB(ks+1, bi^1);   // +4 VMEM
      asm volatile("s_waitcnt vmcnt(6)\n\ts_barrier" ::: "memory");
    } else {
      asm volatile("s_waitcnt vmcnt(0)\n\ts_barrier" ::: "memory");
    }
    __builtin_amdgcn_sched_barrier(0);
    bf16x8 a[4], b[4];
    #pragma unroll
    for (int ni=0;ni<4;++ni){
      int nn = c0 + ni*16 + l15;
      b[ni] = *(const bf16x8*)((const char*)&Bl[bi][0]
               + (size_t)nn*64 + (size_t)((lq ^ ((nn>>1)&3))*16));
    }
    #pragma unroll
    for (int mi=0;mi<4;++mi){
      int rw = mi*16 + l15;
      int sw = l15 & 7;
      const char* ab = (const char*)&Afl[bi][0] + (size_t)rw*128;
      f32x4 f0 = *(const f32x4*)(ab + (size_t)(((lq*2+0)^sw))*16);
      f32x4 f1 = *(const f32x4*)(ab + (size_t)(((lq*2+1)^sw))*16);
      bf16x8 o;
      o[0]=(bf16)f0[0]; o[1]=(bf16)f0[1]; o[2]=(bf16)f0[2]; o[3]=(bf16)f0[3];
      o[4]=(bf16)f1[0]; o[5]=(bf16)f1[1]; o[6]=(bf16)f1[2]; o[7]=(bf16)f1[3];
      a[mi] = o;
    }
    asm volatile("s_waitcnt lgkmcnt(0)" ::: "memory");
    __builtin_amdgcn_sched_barrier(0);
    #pragma unroll
    for (int mi=0;mi<4;++mi)
      #pragma unroll
      for (int ni=0;ni<4;++ni)
        acc[mi][ni] = __builtin_amdgcn_mfma_f32_16x16x32_bf16(b[ni], a[mi], acc[mi][ni], 0,0,0);
    if (ks < 7)
      __builtin_amdgcn_s_barrier();   // readers of buf bi done before stage(ks+2) overwrites
  }
#undef STAGEA
#undef STAGEB

  // ---- epilogue: add P[src]+Q[dst]+bias, relu in place ----
  float4 bias4[4];
  #pragma unroll
  for (int ni=0;ni<4;++ni)
    bias4[ni] = *(const float4*)(bfused + c0 + ni*16 + lq*4);

  #pragma unroll
  for (int mi=0;mi<4;++mi){
    int row = mi*16 + l15;
    int srow = sIl[row], drow = dIl[row];
    #pragma unroll
    for (int ni=0;ni<4;++ni){
      bf16x4 pv = *(const bf16x4*)(P + (size_t)srow*256 + c0 + ni*16 + lq*4);
      bf16x4 qv = *(const bf16x4*)(Q + (size_t)drow*256 + c0 + ni*16 + lq*4);
      f32x4 t4 = acc[mi][ni];
      t4[0] = fmaxf(t4[0] + (float)pv[0] + (float)qv[0] + bias4[ni].x, 0.f);
      t4[1] = fmaxf(t4[1] + (float)pv[1] + (float)qv[1] + bias4[ni].y, 0.f);
      t4[2] = fmaxf(t4[2] + (float)pv[2] + (float)qv[2] + bias4[ni].z, 0.f);
      t4[3] = fmaxf(t4[3] + (float)pv[3] + (float)qv[3] + bias4[ni].w, 0.f);
      acc[mi][ni] = t4;
    }
  }

  // ---- segment reduce per run (r6-verified mapping) ----
  int nR = nRunS;
  for (int k=0; k<nR; ++k){
    int rs = runS[k], re = runS[k+1], tr = runT[k];
    float part16[16];
    #pragma unroll
    for (int ni=0;ni<4;++ni){
      #pragma unroll
      for (int q=0;q<4;++q){
        float s = 0.f;
        #pragma unroll
        for (int mi=0;mi<4;++mi){
          int row = mi*16 + l15;
          s += (row >= rs && row < re) ? acc[mi][ni][q] : 0.f;
        }
        part16[ni*4+q] = s;
      }
    }
    #pragma unroll
    for (int m=1; m<16; m<<=1){
      #pragma unroll
      for (int s=0;s<16;++s) part16[s] += __shfl_xor(part16[s], m);
    }
    float v = part16[0];
    #pragma unroll
    for (int s=1;s<16;++s) v = (l15==s) ? part16[s] : v;
    atomicAdd(&rel_sum[(size_t)tr*256 + c0 + ((l15>>2)<<4) + (lq<<2) + (l15&3)], v);
  }
}

// rel_bf[tr][c] = bf16(rel_sum/count) or 0
__global__ void k_mean(const float* __restrict__ rel_sum, const int* __restrict__ counts,
                       bf16* __restrict__ rel_bf){
  int tr = blockIdx.x, c = threadIdx.x;
  int cnt = counts[tr];
  float v = (cnt > 0) ? rel_sum[(size_t)tr*256 + c] / (float)cnt : 0.f;
  rel_bf[(size_t)tr*256 + c] = (bf16)v;
}

// ---------------- plain bf16 GEMM (GI), K=256, out f32 stride 768 ----------------
__global__ __launch_bounds__(256) void k_gemm(
    const bf16* __restrict__ A, const bf16* __restrict__ BT,
    const float* __restrict__ bias, float* __restrict__ Out)
{
  int m0 = blockIdx.x*128, n0 = blockIdx.y*128;
  int tid = threadIdx.x, lane = tid&63, w = tid>>6;
  int l15 = lane&15, lq = lane>>4;
  __shared__ __align__(16) bf16 Al[128*32];
  __shared__ __align__(16) bf16 Bl[128*32];
  int wr = (w&1)*64, wc = (w>>1)*64;
  f32x4 acc[4][4];
  f32x4 z4 = {0.f,0.f,0.f,0.f};
  #pragma unroll
  for (int mi=0;mi<4;++mi)
    #pragma unroll
    for (int ni=0;ni<4;++ni) acc[mi][ni]=z4;
  for (int ks=0; ks<8; ++ks){
    int k0 = ks*32;
    #pragma unroll
    for (int p=0;p<2;++p){
      int c = p*256 + tid;
      int rw = c>>2, part = c&3;
      int pp = part ^ ((rw>>1)&3);
      const char* src = (const char*)(A + (size_t)(m0+rw)*256 + k0) + pp*16;
      gload16(src, (char*)Al + (size_t)(p*256 + w*64)*16);
    }
    #pragma unroll
    for (int p=0;p<2;++p){
      int c = p*256 + tid;
      int nn = c>>2, part = c&3;
      int pp = part ^ ((nn>>1)&3);
      const char* src = (const char*)(BT + (size_t)(n0+nn)*256 + k0) + pp*16;
      gload16(src, (char*)Bl + (size_t)(p*256 + w*64)*16);
    }
    __syncthreads();
    bf16x8 a[4], b[4];
    #pragma unroll
    for (int mi=0;mi<4;++mi){
      int rw = wr + mi*16 + l15;
      a[mi] = *(const bf16x8*)((const char*)Al + (size_t)rw*64 + (size_t)((lq ^ ((rw>>1)&3))*16));
    }
    #pragma unroll
    for (int ni=0;ni<4;++ni){
      int nn = wc + ni*16 + l15;
      b[ni] = *(const bf16x8*)((const char*)Bl + (size_t)nn*64 + (size_t)((lq ^ ((nn>>1)&3))*16));
    }
    #pragma unroll
    for (int mi=0;mi<4;++mi)
      #pragma unroll
      for (int ni=0;ni<4;++ni)
        acc[mi][ni] = __builtin_amdgcn_mfma_f32_16x16x32_bf16(a[mi], b[ni], acc[mi][ni], 0,0,0);
    __syncthreads();
  }
  #pragma unroll
  for (int ni=0;ni<4;++ni){
    int col = n0 + wc + ni*16 + l15;
    float bv = bias[col];
    #pragma unroll
    for (int mi=0;mi<4;++mi){
      #pragma unroll
      for (int q=0;q<4;++q){
        int row = m0 + wr + mi*16 + lq*4 + q;
        Out[(size_t)row*768 + col] = acc[mi][ni][q] + bv;
      }
    }
  }
}

// ---------------- fused whole-sequence GRU ----------------
__global__ __launch_bounds__(256) void k_gru(
    const float* __restrict__ GI, const bf16* __restrict__ WhhT,
    const float* __restrict__ bhh, const int* __restrict__ time_idx,
    float* __restrict__ out)
{
  int blk = blockIdx.x;           // 16 rows: blk*16 .. blk*16+15
  int tid = threadIdx.x, lane = tid&63, w = tid>>6;
  int l15 = lane&15, lq = lane>>4;
  int b = blk >> 4;               // batch index (256 rows per b)
  int rr = ((blk & 15)*16) + l15; // rel index of this lane's row
  __shared__ __align__(16) bf16 Ah[16*256];   // 8KB h rows (bf16)

  f32x4 h[4];
  #pragma unroll
  for (int jq=0;jq<4;++jq) h[jq] = f32x4{0.f,0.f,0.f,0.f};

  for (int s=0; s<SEQQ; ++s){
    int t = time_idx[b*SEQQ + s];
    size_t gib = (size_t)(t*256 + rr)*768;
    f32x4 gh[12];
    #pragma unroll
    for (int ni=0;ni<12;++ni){
      int col = (ni>>2)*256 + w*64 + (ni&3)*16 + lq*4;
      gh[ni] = *(const f32x4*)(bhh + col);
    }
    if (s > 0){
      #pragma unroll
      for (int ks=0; ks<8; ++ks){
        bf16x8 a = *(const bf16x8*)(&Ah[0] + (size_t)l15*256 + ks*32 + lq*8);
        #pragma unroll
        for (int ni=0;ni<12;++ni){
          int n = (ni>>2)*256 + w*64 + (ni&3)*16 + l15;
          bf16x8 wv = *(const bf16x8*)(WhhT + (size_t)n*256 + ks*32 + lq*8);
          gh[ni] = __builtin_amdgcn_mfma_f32_16x16x32_bf16(wv, a, gh[ni], 0,0,0);
        }
      }
    }
    #pragma unroll
    for (int jq=0;jq<4;++jq){
      int col = w*64 + jq*16 + lq*4;
      f32x4 ir = *(const f32x4*)(GI + gib + col);
      f32x4 iz = *(const f32x4*)(GI + gib + 256 + col);
      f32x4 in = *(const f32x4*)(GI + gib + 512 + col);
      #pragma unroll
      for (int q=0;q<4;++q){
        float rg = 1.f/(1.f + __expf(-(ir[q] + gh[jq][q])));
        float zz = 1.f/(1.f + __expf(-(iz[q] + gh[4+jq][q])));
        float nn = tanhf(in[q] + rg*gh[8+jq][q]);
        h[jq][q] = (1.f - zz)*nn + zz*h[jq][q];
      }
    }
    if (s < SEQQ-1){
      __syncthreads();
      #pragma unroll
      for (int jq=0;jq<4;++jq){
        bf16x4 o;
        #pragma unroll
        for (int q=0;q<4;++q) o[q] = (bf16)h[jq][q];
        *(bf16x4*)(&Ah[0] + (size_t)l15*256 + w*64 + jq*16 + lq*4) = o;
      }
      __syncthreads();
    }
  }
  #pragma unroll
  for (int jq=0;jq<4;++jq){
    f32x4 o = h[jq];
    *(f32x4*)(out + (size_t)(blk*16 + l15)*256 + w*64 + jq*16 + lq*4) = o;
  }
}

// ---------------- launch ----------------
extern "C" void kernel_launch(void* const* d_in, const int* in_sizes, int n_in,
                              void* d_out, int out_size, void* d_ws, size_t ws_size,
                              hipStream_t stream)
{
  (void)in_sizes; (void)n_in; (void)out_size; (void)ws_size;
  const float* node_embeds = (const float*)d_in[0];
  const float* text_emb    = (const float*)d_in[1];
  const float* text_w_W    = (const float*)d_in[2];
  const float* text_w_b    = (const float*)d_in[3];
  const float* edge_w_W    = (const float*)d_in[4];
  const float* edge_w_b    = (const float*)d_in[5];
  const float* gru_Wih     = (const float*)d_in[6];
  const float* gru_Whh     = (const float*)d_in[7];
  const float* gru_bih     = (const float*)d_in[8];
  const float* gru_bhh     = (const float*)d_in[9];
  const int* edge_src      = (const int*)d_in[10];
  const int* edge_dst      = (const int*)d_in[11];
  const int* edge_rel      = (const int*)d_in[12];
  const int* time_idx      = (const int*)d_in[13];
  float* out = (float*)d_out;
  char* ws = (char*)d_ws;

  size_t o = 0;
  bf16*  WbT    = (bf16*) (ws + o); o += (size_t)768*256*2;
  bf16*  WihT   = (bf16*) (ws + o); o += (size_t)768*256*2;
  bf16*  WhhT   = (bf16*) (ws + o); o += (size_t)768*256*2;
  float* bfused = (float*)(ws + o); o += 1024;
  bf16*  node_bf= (bf16*) (ws + o); o += (size_t)NPAD*256*2;      // 25.6MB
  int*   counts = (int*)  (ws + o); o += (size_t)TT*256*4;
  int*   offs   = (int*)  (ws + o); o += (size_t)TT*256*4;
  int*   cursor = (int*)  (ws + o); o += (size_t)TT*256*4;
  int*   gperm  = (int*)  (ws + o); o += (size_t)TT*EE*4;
  int*   src_p  = (int*)  (ws + o); o += (size_t)TT*EE*4;
  int*   dst_p  = (int*)  (ws + o); o += (size_t)TT*EE*4;
  int*   tr_p   = (int*)  (ws + o); o += (size_t)TT*EE*4;
  bf16*  rel_bf = (bf16*) (ws + o); o += (size_t)TT*256*256*2;
  bf16*  P      = (bf16*) (ws + o); o += (size_t)NPAD*256*2;      // 25.6MB
  bf16*  Q      = (bf16*) (ws + o); o += (size_t)NPAD*256*2;      // 25.6MB
  float* rel_sum= (float*)(ws + o); o += (size_t)TT*256*256*4;    // 6.3MB
  float* GI     = (float*)(ws + o); o += (size_t)TT*256*768*4;    // 18.9MB

  k_cvt8<<<6250,256,0,stream>>>(node_embeds, node_bf, NNODES*256/8);
  k_build_wbt<<<256,256,0,stream>>>(text_w_W, edge_w_W, WbT);
  k_bias<<<1,256,0,stream>>>(text_w_b, edge_w_W, edge_w_b, bfused);
  k_gruWT<<<768,256,0,stream>>>(gru_Wih, WihT);
  k_gruWT<<<768,256,0,stream>>>(gru_Whh, WhhT);
  k_hist<<<TT,256,0,stream>>>(edge_rel, counts, offs, cursor);
  k_perm<<<dim3((EE+255)/256,TT),256,0,stream>>>(edge_rel, edge_src, edge_dst,
                                                 cursor, gperm, src_p, dst_p, tr_p);
  k_projn<<<NPAD/128,256,0,stream>>>(node_bf, WbT, 0,   P);
  k_projn<<<NPAD/128,256,0,stream>>>(node_bf, WbT, 512, Q);
  hipMemsetAsync(rel_sum, 0, (size_t)TT*256*256*4, stream);
  k_projtc<<<TT*EE/64,256,0,stream>>>(text_emb, gperm, WbT, bfused, P, Q,
                                      src_p, dst_p, tr_p, rel_sum);
  k_mean<<<TT*256,256,0,stream>>>(rel_sum, counts, rel_bf);
  // GI = rel_emb @ Wih + bih  (M=6144)
  k_gemm<<<dim3(48,6),256,0,stream>>>(rel_bf, WihT, gru_bih, GI);
  // whole GRU sequence in one kernel
  k_gru<<<256,256,0,stream>>>(GI, WhhT, gru_bhh, time_idx, out);
}